// Round 1
// baseline (96.870 us; speedup 1.0000x reference)
//
#include <hip/hip_runtime.h>
#include <math.h>

#define NTX 3
#define NAX 2048
#define NEL 128
#define NPIX (512*256)

// FS / SOUND_SPEED
constexpr float DELAY_SCALE = 20000000.0f / 1540.0f;

// Transpose data (tx, ax, el) -> (tx, el, ax) so each element's time series is
// contiguous (gathers then hit few cachelines).
__global__ __launch_bounds__(256) void transpose_k(const float* __restrict__ in,
                                                   float* __restrict__ out) {
  __shared__ float tile[32][33];
  const int t = blockIdx.z;
  const int ax0 = blockIdx.x * 32;
  const int el0 = blockIdx.y * 32;
  const float* inp = in + (size_t)t * (NAX * NEL);
  float* outp = out + (size_t)t * (NEL * NAX);
  const int lx = threadIdx.x;  // 0..31
  const int ly = threadIdx.y;  // 0..7
#pragma unroll
  for (int i = 0; i < 32; i += 8)
    tile[ly + i][lx] = inp[(ax0 + ly + i) * NEL + (el0 + lx)];
  __syncthreads();
#pragma unroll
  for (int i = 0; i < 32; i += 8)
    outp[(el0 + ly + i) * NAX + (ax0 + lx)] = tile[lx][ly + i];
}

// COLSTRIDE == 1   : cols is transposed (tx, el, ax)
// COLSTRIDE == NEL : cols is original (tx, ax, el)
template <int COLSTRIDE>
__global__ __launch_bounds__(256) void das_k(const float* __restrict__ cols,
                                             const float* __restrict__ grid,
                                             const float* __restrict__ probe,
                                             const float* __restrict__ angles,
                                             float* __restrict__ out) {
  __shared__ float s_ex[NEL];
  __shared__ float s_part[256];
  const int tid = threadIdx.x;
  if (tid < NEL) s_ex[tid] = probe[3 * tid];
  __syncthreads();

  // block = 64 pixels x 4 element-chunks (for occupancy)
  const int pix = blockIdx.x * 64 + (tid & 63);
  const int chunk = tid >> 6;

  const float px = grid[3 * pix + 0];
  const float pz = grid[3 * pix + 2];
  const float z2 = pz * pz;
  const float half_ap = pz * 0.5f;  // (z / F_NUMBER) / 2, F# = 1

  float dtx[NTX];
#pragma unroll
  for (int t = 0; t < NTX; ++t) {
    const float a = angles[t];
    dtx[t] = px * sinf(a) + pz * cosf(a);
  }

  float acc = 0.0f;
  const int el_begin = chunk * 32;
#pragma unroll 4
  for (int el = el_begin; el < el_begin + 32; ++el) {
    const float ex = s_ex[el];
    const float dx = px - ex;
    if (fabsf(dx) > half_ap) continue;  // apodization mask == 0
    const float drx = sqrtf(dx * dx + z2);
#pragma unroll
    for (int t = 0; t < NTX; ++t) {
      const float w = (dtx[t] + drx) * DELAY_SCALE;
      int i0 = (int)floorf(w);
      i0 = i0 < 0 ? 0 : (i0 > NAX - 1 ? NAX - 1 : i0);
      const int i1 = (i0 + 1 > NAX - 1) ? NAX - 1 : i0 + 1;
      const float* col;
      if (COLSTRIDE == 1)
        col = cols + ((size_t)t * NEL + el) * NAX;
      else
        col = cols + (size_t)t * (NAX * NEL) + el;
      const float s0 = col[(size_t)i0 * COLSTRIDE];
      const float s1 = col[(size_t)i1 * COLSTRIDE];
      acc += ((float)i1 - w) * s0 + (w - (float)i0) * s1;
    }
  }
  s_part[tid] = acc;
  __syncthreads();
  if (tid < 64) {
    out[pix] = s_part[tid] + s_part[tid + 64] + s_part[tid + 128] + s_part[tid + 192];
  }
}

extern "C" void kernel_launch(void* const* d_in, const int* in_sizes, int n_in,
                              void* d_out, int out_size, void* d_ws, size_t ws_size,
                              hipStream_t stream) {
  const float* data = (const float*)d_in[0];    // (1, 3, 2048, 128, 1)
  const float* grid = (const float*)d_in[1];    // (131072, 3)
  const float* probe = (const float*)d_in[2];   // (128, 3)
  const float* angles = (const float*)d_in[3];  // (3,)
  float* out = (float*)d_out;                   // (1, 512, 256)

  const size_t tbytes = (size_t)NTX * NAX * NEL * sizeof(float);
  if (ws_size >= tbytes) {
    float* dT = (float*)d_ws;
    dim3 tb(32, 8);
    dim3 tg(NAX / 32, NEL / 32, NTX);
    transpose_k<<<tg, tb, 0, stream>>>(data, dT);
    das_k<1><<<NPIX / 64, 256, 0, stream>>>(dT, grid, probe, angles, out);
  } else {
    das_k<NEL><<<NPIX / 64, 256, 0, stream>>>(data, grid, probe, angles, out);
  }
}

// Round 2
// 91.654 us; speedup vs baseline: 1.0569x; 1.0569x over previous
//
#include <hip/hip_runtime.h>
#include <math.h>

#define NTX 3
#define NAX 2048
#define NEL 128
#define NPIX (512*256)

// FS / SOUND_SPEED
constexpr float DELAY_SCALE = 20000000.0f / 1540.0f;

// Build pairs[t][el][ax] = (data[t][ax][el], data[t][ax+1][el]) as float2.
// LDS-tiled transpose: read coalesced over el, write coalesced over ax.
__global__ __launch_bounds__(256) void make_pairs_k(const float* __restrict__ in,
                                                    float2* __restrict__ out) {
  __shared__ float tile[33][33];  // [ax_local 0..32][el_local 0..31], +1 pad col
  const int t = blockIdx.z;
  const int ax0 = blockIdx.x * 32;
  const int el0 = blockIdx.y * 32;
  const float* inp = in + (size_t)t * (NAX * NEL);
  float2* outp = out + (size_t)t * (NEL * NAX);
  const int lx = threadIdx.x;  // 0..31
  const int ly = threadIdx.y;  // 0..7
  // load 33 ax rows (need ax+1 for the pair); clamp last row
#pragma unroll
  for (int i = 0; i < 40; i += 8) {
    const int r = ly + i;
    if (r < 33) {
      const int ax = ax0 + r > NAX - 1 ? NAX - 1 : ax0 + r;
      tile[r][lx] = inp[(size_t)ax * NEL + (el0 + lx)];
    }
  }
  __syncthreads();
  // write: lane lx -> ax_local, ly+i -> el_local ; coalesced float2 stores
#pragma unroll
  for (int i = 0; i < 32; i += 8) {
    const int e = ly + i;
    float2 p;
    p.x = tile[lx][e];
    p.y = tile[lx + 1][e];
    outp[(size_t)(el0 + e) * NAX + (ax0 + lx)] = p;
  }
}

__global__ __launch_bounds__(512) void das2_k(const float2* __restrict__ pairs,
                                              const float* __restrict__ grid,
                                              const float* __restrict__ probe,
                                              const float* __restrict__ angles,
                                              float* __restrict__ out) {
  __shared__ float s_ex[NEL];
  __shared__ float s_part[512];
  const int tid = threadIdx.x;
  if (tid < NEL) s_ex[tid] = probe[3 * tid];
  __syncthreads();

  // block = 64 pixels (consecutive x) x 8 element-chunks of 16
  const int pix = blockIdx.x * 64 + (tid & 63);
  const int chunk = tid >> 6;

  const float px = grid[3 * pix + 0];
  const float pz = grid[3 * pix + 2];
  const float z2 = pz * pz;
  const float half_ap = pz * 0.5f;  // (z / F_NUMBER) / 2, F# = 1

  float wtx[NTX];
#pragma unroll
  for (int t = 0; t < NTX; ++t) {
    const float a = angles[t];
    wtx[t] = (px * sinf(a) + pz * cosf(a)) * DELAY_SCALE;
  }

  float acc = 0.0f;
  const int el_begin = chunk * 16;
#pragma unroll 2
  for (int el = el_begin; el < el_begin + 16; ++el) {
    const float ex = s_ex[el];
    const float dx = px - ex;
    if (fabsf(dx) > half_ap) continue;  // apodization mask == 0
    const float base = sqrtf(dx * dx + z2) * DELAY_SCALE;
#pragma unroll
    for (int t = 0; t < NTX; ++t) {
      const float w = base + wtx[t];
      // w <= ~1498 < 2047: upper clamps never fire; trunc==floor after 0-clamp
      int i0 = (int)w;
      i0 = i0 < 0 ? 0 : i0;
      const float2 p = pairs[((size_t)t * NEL + el) * NAX + i0];
      const float fi0 = (float)i0;
      const float f1 = w - fi0;   // == w - d0f (exact)
      const float f0 = 1.0f - f1; // == d1f - w (exact)
      acc = fmaf(f0, p.x, fmaf(f1, p.y, acc));
    }
  }
  s_part[tid] = acc;
  __syncthreads();
  if (tid < 64) {
    float s = 0.0f;
#pragma unroll
    for (int k = 0; k < 8; ++k) s += s_part[tid + 64 * k];
    out[pix] = s;
  }
}

// Fallback (no workspace): original layout, two scalar loads.
__global__ __launch_bounds__(512) void das_fb_k(const float* __restrict__ data,
                                                const float* __restrict__ grid,
                                                const float* __restrict__ probe,
                                                const float* __restrict__ angles,
                                                float* __restrict__ out) {
  __shared__ float s_ex[NEL];
  __shared__ float s_part[512];
  const int tid = threadIdx.x;
  if (tid < NEL) s_ex[tid] = probe[3 * tid];
  __syncthreads();
  const int pix = blockIdx.x * 64 + (tid & 63);
  const int chunk = tid >> 6;
  const float px = grid[3 * pix + 0];
  const float pz = grid[3 * pix + 2];
  const float z2 = pz * pz;
  const float half_ap = pz * 0.5f;
  float wtx[NTX];
#pragma unroll
  for (int t = 0; t < NTX; ++t) {
    const float a = angles[t];
    wtx[t] = (px * sinf(a) + pz * cosf(a)) * DELAY_SCALE;
  }
  float acc = 0.0f;
  const int el_begin = chunk * 16;
  for (int el = el_begin; el < el_begin + 16; ++el) {
    const float ex = s_ex[el];
    const float dx = px - ex;
    if (fabsf(dx) > half_ap) continue;
    const float base = sqrtf(dx * dx + z2) * DELAY_SCALE;
#pragma unroll
    for (int t = 0; t < NTX; ++t) {
      const float w = base + wtx[t];
      int i0 = (int)w;
      i0 = i0 < 0 ? 0 : i0;
      const float* col = data + (size_t)t * (NAX * NEL) + el;
      const float s0 = col[(size_t)i0 * NEL];
      const float s1 = col[(size_t)(i0 + 1) * NEL];
      const float fi0 = (float)i0;
      const float f1 = w - fi0;
      acc = fmaf(1.0f - f1, s0, fmaf(f1, s1, acc));
    }
  }
  s_part[tid] = acc;
  __syncthreads();
  if (tid < 64) {
    float s = 0.0f;
#pragma unroll
    for (int k = 0; k < 8; ++k) s += s_part[tid + 64 * k];
    out[pix] = s;
  }
}

extern "C" void kernel_launch(void* const* d_in, const int* in_sizes, int n_in,
                              void* d_out, int out_size, void* d_ws, size_t ws_size,
                              hipStream_t stream) {
  const float* data = (const float*)d_in[0];    // (1, 3, 2048, 128, 1)
  const float* grid = (const float*)d_in[1];    // (131072, 3)
  const float* probe = (const float*)d_in[2];   // (128, 3)
  const float* angles = (const float*)d_in[3];  // (3,)
  float* out = (float*)d_out;                   // (1, 512, 256)

  const size_t pbytes = (size_t)NTX * NEL * NAX * sizeof(float2);  // 6 MB
  if (ws_size >= pbytes) {
    float2* pairs = (float2*)d_ws;
    dim3 tb(32, 8);
    dim3 tg(NAX / 32, NEL / 32, NTX);
    make_pairs_k<<<tg, tb, 0, stream>>>(data, pairs);
    das2_k<<<NPIX / 64, 512, 0, stream>>>(pairs, grid, probe, angles, out);
  } else {
    das_fb_k<<<NPIX / 64, 512, 0, stream>>>(data, grid, probe, angles, out);
  }
}

// Round 4
// 88.050 us; speedup vs baseline: 1.1002x; 1.0409x over previous
//
#include <hip/hip_runtime.h>
#include <math.h>

#define NTX 3
#define NAX 2048
#define NEL 128
#define NPIX (512*256)

// FS / SOUND_SPEED
constexpr float DELAY_SCALE = 20000000.0f / 1540.0f;

typedef _Float16 half2_t __attribute__((ext_vector_type(2)));

// Build pairs[t][el][ax] = (data[t][ax][el], data[t][ax+1][el]) as half2 (4 B).
// 3 MB total -> fits each XCD's 4 MiB L2. LDS-tiled transpose.
__global__ __launch_bounds__(256) void make_pairs_k(const float* __restrict__ in,
                                                    half2_t* __restrict__ out) {
  __shared__ float tile[33][33];  // [ax_local 0..32][el_local 0..31]
  const int t = blockIdx.z;
  const int ax0 = blockIdx.x * 32;
  const int el0 = blockIdx.y * 32;
  const float* inp = in + (size_t)t * (NAX * NEL);
  half2_t* outp = out + (size_t)t * (NEL * NAX);
  const int lx = threadIdx.x;  // 0..31
  const int ly = threadIdx.y;  // 0..7
#pragma unroll
  for (int i = 0; i < 40; i += 8) {
    const int r = ly + i;
    if (r < 33) {
      const int ax = ax0 + r > NAX - 1 ? NAX - 1 : ax0 + r;
      tile[r][lx] = inp[(size_t)ax * NEL + (el0 + lx)];
    }
  }
  __syncthreads();
#pragma unroll
  for (int i = 0; i < 32; i += 8) {
    const int e = ly + i;
    half2_t p;
    p.x = (_Float16)tile[lx][e];
    p.y = (_Float16)tile[lx + 1][e];
    outp[(size_t)(el0 + e) * NAX + (ax0 + lx)] = p;
  }
}

__global__ __launch_bounds__(256) void das_h_k(const half2_t* __restrict__ pairs,
                                               const float* __restrict__ grid,
                                               const float* __restrict__ probe,
                                               const float* __restrict__ angles,
                                               float* __restrict__ out) {
  __shared__ float s_ex[NEL];
  __shared__ float s_part[256];
  const int tid = threadIdx.x;
  if (tid < NEL) s_ex[tid] = probe[3 * tid];
  __syncthreads();

  // block = 64 pixels (consecutive x, same z) x 4 element-chunks of 32
  const int pix = blockIdx.x * 64 + (tid & 63);
  const int chunk = tid >> 6;

  const float px = grid[3 * pix + 0];
  const float pz = grid[3 * pix + 2];
  const float z2 = pz * pz;
  const float half_ap = pz * 0.5f;  // (z / F_NUMBER) / 2, F# = 1

  float wtx[NTX];
#pragma unroll
  for (int t = 0; t < NTX; ++t) {
    const float a = angles[t];
    wtx[t] = (px * sinf(a) + pz * cosf(a)) * DELAY_SCALE;
  }

  float acc = 0.0f;
  const int el_begin = chunk * 32;
#pragma unroll 2
  for (int e = 0; e < 32; ++e) {
    const int el = el_begin + e;
    const float ex = s_ex[el];
    const float dx = px - ex;
    if (fabsf(dx) > half_ap) continue;  // apodization mask == 0 (exact vs ref)
    const float base = sqrtf(fmaf(dx, dx, z2)) * DELAY_SCALE;
    const half2_t* col = pairs + ((size_t)el << 11);
#pragma unroll
    for (int t = 0; t < NTX; ++t) {
      const float w = base + wtx[t];
      // max delay ~1418 < 2047: upper clamp never fires; trunc==floor after 0-clamp
      int i0 = (int)w;
      i0 = i0 < 0 ? 0 : i0;
      const half2_t p = col[((size_t)t << 18) + i0];
      const float fi0 = (float)i0;
      const float f1 = w - fi0;   // == w - d0f
      const float f0 = 1.0f - f1; // == d1f - w
      const half2_t wh = __builtin_bit_cast(half2_t, __builtin_amdgcn_cvt_pkrtz(f0, f1));
      acc = __builtin_amdgcn_fdot2(wh, p, acc, false);
    }
  }
  s_part[tid] = acc;
  __syncthreads();
  if (tid < 64) {
    out[pix] = s_part[tid] + s_part[tid + 64] + s_part[tid + 128] + s_part[tid + 192];
  }
}

// Fallback (no workspace): original layout, two scalar loads, fp32.
__global__ __launch_bounds__(256) void das_fb_k(const float* __restrict__ data,
                                                const float* __restrict__ grid,
                                                const float* __restrict__ probe,
                                                const float* __restrict__ angles,
                                                float* __restrict__ out) {
  __shared__ float s_ex[NEL];
  __shared__ float s_part[256];
  const int tid = threadIdx.x;
  if (tid < NEL) s_ex[tid] = probe[3 * tid];
  __syncthreads();
  const int pix = blockIdx.x * 64 + (tid & 63);
  const int chunk = tid >> 6;
  const float px = grid[3 * pix + 0];
  const float pz = grid[3 * pix + 2];
  const float z2 = pz * pz;
  const float half_ap = pz * 0.5f;
  float wtx[NTX];
#pragma unroll
  for (int t = 0; t < NTX; ++t) {
    const float a = angles[t];
    wtx[t] = (px * sinf(a) + pz * cosf(a)) * DELAY_SCALE;
  }
  float acc = 0.0f;
  const int el_begin = chunk * 32;
  for (int e = 0; e < 32; ++e) {
    const int el = el_begin + e;
    const float ex = s_ex[el];
    const float dx = px - ex;
    if (fabsf(dx) > half_ap) continue;
    const float base = sqrtf(fmaf(dx, dx, z2)) * DELAY_SCALE;
#pragma unroll
    for (int t = 0; t < NTX; ++t) {
      const float w = base + wtx[t];
      int i0 = (int)w;
      i0 = i0 < 0 ? 0 : i0;
      const float* colp = data + (size_t)t * (NAX * NEL) + el;
      const float s0 = colp[(size_t)i0 * NEL];
      const float s1 = colp[(size_t)(i0 + 1) * NEL];
      const float f1 = w - (float)i0;
      acc = fmaf(1.0f - f1, s0, fmaf(f1, s1, acc));
    }
  }
  s_part[tid] = acc;
  __syncthreads();
  if (tid < 64) {
    out[pix] = s_part[tid] + s_part[tid + 64] + s_part[tid + 128] + s_part[tid + 192];
  }
}

extern "C" void kernel_launch(void* const* d_in, const int* in_sizes, int n_in,
                              void* d_out, int out_size, void* d_ws, size_t ws_size,
                              hipStream_t stream) {
  const float* data = (const float*)d_in[0];    // (1, 3, 2048, 128, 1)
  const float* grid = (const float*)d_in[1];    // (131072, 3)
  const float* probe = (const float*)d_in[2];   // (128, 3)
  const float* angles = (const float*)d_in[3];  // (3,)
  float* out = (float*)d_out;                   // (1, 512, 256)

  const size_t pbytes = (size_t)NTX * NEL * NAX * sizeof(half2_t);  // 3 MB
  if (ws_size >= pbytes) {
    half2_t* pairs = (half2_t*)d_ws;
    dim3 tb(32, 8);
    dim3 tg(NAX / 32, NEL / 32, NTX);
    make_pairs_k<<<tg, tb, 0, stream>>>(data, pairs);
    das_h_k<<<NPIX / 64, 256, 0, stream>>>(pairs, grid, probe, angles, out);
  } else {
    das_fb_k<<<NPIX / 64, 256, 0, stream>>>(data, grid, probe, angles, out);
  }
}